// Round 7
// baseline (98.305 us; speedup 1.0000x reference)
//
#include <hip/hip_runtime.h>
#include <stdint.h>

// z (32,384,28,28) fp32; codebook (2048,384) fp32.
// N tokens = 25088, D = 384, K = 2048. out = z_q (9633792 f32) + loss (1 f32).
#define M_TOK 25088
#define D_DIM 384
#define K_CB  2048
#define OUT_ELEMS 9633792

typedef __attribute__((ext_vector_type(8))) short short8;
typedef __attribute__((ext_vector_type(4))) float f32x4;

static __device__ __forceinline__ unsigned short f2bf(float f) {
    uint32_t u = __float_as_uint(f);
    u += 0x7FFF + ((u >> 16) & 1);   // RNE
    return (unsigned short)(u >> 16);
}
static __device__ __forceinline__ float bf2f(unsigned short h) {
    return __uint_as_float(((uint32_t)h) << 16);
}
static __device__ __forceinline__ void gl_lds16(const void* g, void* l) {
    __builtin_amdgcn_global_load_lds((const __attribute__((address_space(1))) void*)g,
                                     (__attribute__((address_space(3))) void*)l,
                                     16, 0, 0);
}

// ---------------- fused: z transpose (+ ||z||^2 partials) and codebook prep ----------------
__global__ __launch_bounds__(256) void prep_transpose_kernel(
    const float* __restrict__ z, const float* __restrict__ cb,
    unsigned short* __restrict__ zf, float* __restrict__ znp,
    unsigned short* __restrict__ cb16, float* __restrict__ cnorm) {
    __shared__ unsigned short tile[64 * 64];
    __shared__ float zred[4][64];
    int bid = blockIdx.x;
    int t = threadIdx.x;
    if (bid >= 2496) {               // codebook prep: 512 blocks x 4 rows
        int lane = t & 63, wv = t >> 6;
        int row = (bid - 2496) * 4 + wv;
        const float* src = cb + (size_t)row * D_DIM;
        unsigned short* dst = cb16 + (size_t)row * D_DIM;
        float ss = 0.f;
#pragma unroll
        for (int i = 0; i < 6; ++i) {
            float v = src[lane + i * 64];
            dst[lane + i * 64] = f2bf(v);
            ss += v * v;
        }
#pragma unroll
        for (int d = 32; d; d >>= 1) ss += __shfl_xor(ss, d);
        if (lane == 0) cnorm[row] = ss;
        return;
    }
    // transpose path: (b,c,s) fp32 -> (token,c) bf16, 64x64 LDS tiles, XOR swizzle
    int sT = bid % 13;
    int rem = bid / 13;
    int cT = rem % 6;
    int b  = rem / 6;
    int c0 = cT * 64, s0 = sT * 64;
    int ls = t & 63;
    int wv = t >> 6;
    float ss = 0.f;
#pragma unroll
    for (int p = 0; p < 16; ++p) {
        int ci = p * 4 + wv;
        int s = s0 + ls;
        float v = 0.f;
        if (s < 784) v = z[(size_t)(b * 384 + c0 + ci) * 784 + s];
        ss += v * v;
        int cx = ci ^ ((ls & 7) << 3);
        tile[ls * 64 + cx] = f2bf(v);
    }
    zred[wv][ls] = ss;
    __syncthreads();
    if (t < 64) {
        int s = s0 + t;
        if (s < 784)
            znp[cT * M_TOK + b * 784 + s] =
                (zred[0][t] + zred[1][t]) + (zred[2][t] + zred[3][t]);
    }
    int si = t >> 2, sub = t & 3;
    int s = s0 + si;
    if (s >= 784) return;
    int x = si & 7;
    int base0 = ((sub ^ (x >> 1)) << 4) | ((x & 1) << 3);
    int base1 = base0 ^ 8;
    uint4 v0 = *(const uint4*)&tile[si * 64 + base0];
    uint4 v1 = *(const uint4*)&tile[si * 64 + base1];
    size_t ro = (size_t)(b * 784 + s) * 384 + c0 + sub * 16;
    *(uint4*)(zf + ro)     = v0;
    *(uint4*)(zf + ro + 8) = v1;
}

// ---------------- distance GEMM + FULL argmin: A-resident, wave tile 128x64 ----------------
// grid 196 (1 block = 128 tokens). 8 waves; each wave owns 64 cols, spans all
// 128 rows (FLOP per LDS byte = 42.7 vs 21.3 before). A k-major in LDS:
// [12 kc][128 row][64 B], 96 KB. B ring: 2 x 32 KB (512 cols x 64 B = one K32
// of one col-macro). 48 steps = 4 macros x 12 kc; per step 12 ds_read_b128 ->
// 32 MFMA; stage step+2 after post-compute barrier; steady vmcnt(4).

#define BARO do { __builtin_amdgcn_s_barrier(); __builtin_amdgcn_sched_barrier(0); } while (0)
#define WAITN(N) do { asm volatile("s_waitcnt vmcnt(" #N ")" ::: "memory"); \
    __builtin_amdgcn_s_barrier(); __builtin_amdgcn_sched_barrier(0); } while (0)

#define COMPUTE(KS) do { \
    const char* Bp_ = ringB + (((KS) & 1) ? 32768 : 0); \
    short8 b0 = *(const short8*)(Bp_); \
    short8 b1 = *(const short8*)(Bp_ + 1024); \
    short8 b2 = *(const short8*)(Bp_ + 2048); \
    short8 b3 = *(const short8*)(Bp_ + 3072); \
    const char* Ap_ = AbaseR + (KS) * 8192; \
    _Pragma("unroll") for (int mt = 0; mt < 8; ++mt) { \
        short8 av = *(const short8*)(Ap_ + mt * 1024); \
        acc[mt][0] = __builtin_amdgcn_mfma_f32_16x16x32_bf16(av, b0, ((KS)==0) ? zero4 : acc[mt][0], 0, 0, 0); \
        acc[mt][1] = __builtin_amdgcn_mfma_f32_16x16x32_bf16(av, b1, ((KS)==0) ? zero4 : acc[mt][1], 0, 0, 0); \
        acc[mt][2] = __builtin_amdgcn_mfma_f32_16x16x32_bf16(av, b2, ((KS)==0) ? zero4 : acc[mt][2], 0, 0, 0); \
        acc[mt][3] = __builtin_amdgcn_mfma_f32_16x16x32_bf16(av, b3, ((KS)==0) ? zero4 : acc[mt][3], 0, 0, 0); \
    } \
} while (0)

#define SCORE(COLB) do { \
    _Pragma("unroll") for (int nt = 0; nt < 4; ++nt) { \
        int col_ = (COLB) + wave * 64 + nt * 16 + r; \
        float cn1_ = 1.0f + cnorm[col_]; \
        _Pragma("unroll") for (int mt = 0; mt < 8; ++mt) \
        _Pragma("unroll") for (int j = 0; j < 4; ++j) { \
            float s1_ = fmaf(acc[mt][nt][j], -2.0f, cn1_); \
            uint32_t u_ = (__float_as_uint(s1_) & 0xFFFFF800u) | (uint32_t)col_; \
            int sl_ = mt * 4 + j; \
            pmin[sl_] = u_ < pmin[sl_] ? u_ : pmin[sl_]; \
        } \
    } \
} while (0)

#define STAGE(OFF, SLOT) do { \
    const char* s_ = cbB + (OFF); \
    char* d_ = ring + (SLOT) * 32768 + t16; \
    gl_lds16(s_,          d_); \
    gl_lds16(s_ +  98304, d_ + 8192); \
    gl_lds16(s_ + 196608, d_ + 16384); \
    gl_lds16(s_ + 294912, d_ + 24576); \
} while (0)

// full step: compute ks, (score at 11), barrier, stage step+2, vmcnt(4)+barrier
#define STEPK(KS, SMB, COLB) do { \
    COMPUTE(KS); \
    if ((KS) == 11) SCORE(COLB); \
    BARO; \
    STAGE((SMB) + (((KS) <= 9) ? ((KS) + 2) * 64 : 393216 + ((KS) - 10) * 64), (KS) & 1); \
    WAITN(4); \
} while (0)

__global__ __launch_bounds__(512, 2) void argmin7_kernel(
    const unsigned short* __restrict__ zf, const unsigned short* __restrict__ cb16,
    const float* __restrict__ cnorm, int* __restrict__ midx, float* __restrict__ mdist) {
    extern __shared__ char smem[];
    char* As = smem;                  // 96 KB: [kc][row][64B], swizzled
    char* ring = smem + 98304;        // 2 x 32 KB

    int t = threadIdx.x;
    int lane = t & 63, wave = t >> 6;     // wave = col-group 0..7
    int r = lane & 15, q = lane >> 4;
    int blk = blockIdx.x;                 // 196

    // per-lane staging source geometry: row = t>>2 (0..127), byte = (t&3)*16,
    // swizzle ^ ((row&3)<<4) within the 64-byte k-chunk
    uint32_t vb = (uint32_t)(t >> 2) * 768u +
                  ((((uint32_t)t & 3u) * 16u) ^ ((((uint32_t)t >> 2) & 3u) << 4));
    uint32_t t16 = (uint32_t)t * 16u;
    const char* zfA = (const char*)zf + (size_t)blk * 98304 + vb;
    const char* cbB = (const char*)cb16 + vb;

    // ---- prologue: A kc=0..11 (k-major, linear dest), then B steps 0,1 ----
#pragma unroll
    for (int kc = 0; kc < 12; ++kc)
        gl_lds16(zfA + kc * 64, As + kc * 8192 + t16);
    STAGE(0, 0);     // (mc0, ks0) -> slot 0
    STAGE(64, 1);    // (mc0, ks1) -> slot 1

    // fragment read geometry (loop-invariant)
    uint32_t kqb = (((uint32_t)q * 16u) ^ (((uint32_t)r & 3u) << 4));
    const char* AbaseR = As + (uint32_t)r * 64u + kqb;              // + ks*8192 + mt*1024
    const char* ringB = ring + (uint32_t)wave * 4096u + (uint32_t)r * 64u + kqb;

    uint32_t pmin[32];
#pragma unroll
    for (int i = 0; i < 32; ++i) pmin[i] = 0xFFFFFFFFu;
    f32x4 acc[8][4];
    const f32x4 zero4 = {0.f, 0.f, 0.f, 0.f};

    WAITN(4);   // A + B(step0) done; B(step1) in flight

#pragma unroll 1
    for (int mc = 0; mc < 3; ++mc) {
        const uint32_t smb = (uint32_t)mc * 393216u;
        const int colb = mc * 512;
        STEPK(0, smb, colb);  STEPK(1, smb, colb);  STEPK(2, smb, colb);
        STEPK(3, smb, colb);  STEPK(4, smb, colb);  STEPK(5, smb, colb);
        STEPK(6, smb, colb);  STEPK(7, smb, colb);  STEPK(8, smb, colb);
        STEPK(9, smb, colb);  STEPK(10, smb, colb); STEPK(11, smb, colb);
    }
    {   // mc = 3: stages exist only for ks<=9 (steps 38..47)
        const uint32_t smb = 3u * 393216u;
        STEPK(0, smb, 1536);  STEPK(1, smb, 1536);  STEPK(2, smb, 1536);
        STEPK(3, smb, 1536);  STEPK(4, smb, 1536);  STEPK(5, smb, 1536);
        STEPK(6, smb, 1536);  STEPK(7, smb, 1536);  STEPK(8, smb, 1536);
        STEPK(9, smb, 1536);
        COMPUTE(10);
        WAITN(0);            // drain stage(47), barrier
        COMPUTE(11);
        SCORE(1536);
    }

    // ---- final reduce: 16-lane shfl per row-slot, cross-wave via LDS ----
    __syncthreads();
    uint32_t* comb = (uint32_t*)smem;    // [8 wave][128 row] (A region reused)
#pragma unroll
    for (int sl = 0; sl < 32; ++sl) {
        uint32_t v = pmin[sl];
#pragma unroll
        for (int d = 1; d < 16; d <<= 1) {
            uint32_t ov = __shfl_xor(v, d);
            v = ov < v ? ov : v;
        }
        if (r == 0) {
            int row = (sl >> 2) * 16 + q * 4 + (sl & 3);
            comb[wave * 128 + row] = v;
        }
    }
    __syncthreads();
    if (t < 128) {
        uint32_t m = comb[t];
#pragma unroll
        for (int w = 1; w < 8; ++w) {
            uint32_t mw = comb[w * 128 + t];
            m = mw < m ? mw : m;
        }
        int n = blk * 128 + t;
        midx[n]  = (int)(m & 0x7FFu);
        mdist[n] = __uint_as_float(m & 0xFFFFF800u) - 1.0f;
    }
}

// ---------------- gather + output + loss ----------------
__global__ __launch_bounds__(256) void gather_combine_kernel(
    const float* __restrict__ cb, const int* __restrict__ midx,
    const float* __restrict__ mdist, const float* __restrict__ znp,
    float* __restrict__ out) {
    __shared__ unsigned short tile[56 * 392];
    __shared__ int lidx[56];
    int t = threadIdx.x;
    int bid = blockIdx.x;                 // 448 = 32 b * 14 sT
    int b = bid / 14, sT = bid % 14;
    int n0 = b * 784 + sT * 56;
    float lt = 0.f;
    if (t < 56) {
        int n = n0 + t;
        lidx[t] = midx[n];
        float zn = 0.f;
#pragma unroll
        for (int cT = 0; cT < 6; ++cT) zn += znp[cT * M_TOK + n];
        lt = mdist[n] + zn;               // ~ ||z_n - c_idx||^2
    }
    if (t < 64) {
#pragma unroll
        for (int d = 32; d; d >>= 1) lt += __shfl_xor(lt, d);
        if (t == 0) atomicAdd(out + OUT_ELEMS, lt * (1.25f / (float)OUT_ELEMS));
    }
    __syncthreads();
#pragma unroll
    for (int p = 0; p < 21; ++p) {
        int e = (p * 256 + t) * 4;
        int tok = e / 384;
        int c = e - tok * 384;
        int idx = lidx[tok];
        float4 v = *(const float4*)(cb + (size_t)idx * 384 + c);
        uint2 u;
        u.x = (uint32_t)f2bf(v.x) | ((uint32_t)f2bf(v.y) << 16);
        u.y = (uint32_t)f2bf(v.z) | ((uint32_t)f2bf(v.w) << 16);
        *(uint2*)&tile[tok * 392 + c] = u;
    }
    __syncthreads();
#pragma unroll
    for (int p = 0; p < 42; ++p) {
        int pp = p * 256 + t;
        int c = pp / 28;
        int j = (pp - c * 28) * 2;
        float f0 = bf2f(tile[j * 392 + c]);
        float f1 = bf2f(tile[(j + 1) * 392 + c]);
        size_t off = ((size_t)b * 384 + c) * 784 + (size_t)sT * 56 + j;
        float2 o; o.x = f0; o.y = f1;
        *(float2*)(out + off) = o;
    }
}

extern "C" void kernel_launch(void* const* d_in, const int* in_sizes, int n_in,
                              void* d_out, int out_size, void* d_ws, size_t ws_size,
                              hipStream_t stream) {
    const float* z  = (const float*)d_in[0];
    const float* cb = (const float*)d_in[1];
    float* out = (float*)d_out;
    char* ws = (char*)d_ws;

    // zf (token-major bf16 z, 19.3 MB) borrows d_out: fully consumed by
    // argmin7_kernel (prologue A-stage) before gather_combine overwrites d_out.
    unsigned short* zf = (unsigned short*)d_out;

    unsigned short* cb16 = (unsigned short*)ws;            // 1,572,864 B
    float*  cnorm   = (float*)(ws + 1572864);              //     8,192 B
    float*  znp     = (float*)(ws + 1581056);              //   602,112 B
    int*    midx    = (int*)(ws + 2183168);                //   100,352 B
    float*  mdist   = (float*)(ws + 2283520);              //   100,352 B

    hipMemsetAsync((void*)(out + OUT_ELEMS), 0, 4, stream);
    hipFuncSetAttribute((const void*)argmin7_kernel,
                        hipFuncAttributeMaxDynamicSharedMemorySize, 163840);
    prep_transpose_kernel<<<3008, 256, 0, stream>>>(z, cb, zf, znp, cb16, cnorm);
    argmin7_kernel<<<196, 512, 163840, stream>>>(zf, cb16, cnorm, midx, mdist);
    gather_combine_kernel<<<448, 256, 0, stream>>>(cb, midx, mdist, znp, out);
}